// Round 5
// baseline (1594.073 us; speedup 1.0000x reference)
//
#include <hip/hip_runtime.h>
#include <hip/hip_bf16.h>
#include <stdint.h>

#define T_STEPS 512
#define BATCH   128
#define IN      512
#define HID     1024
#define OUTN    256

typedef __bf16 bf16x8 __attribute__((ext_vector_type(8)));
typedef float  f32x4  __attribute__((ext_vector_type(4)));
typedef unsigned short us8 __attribute__((ext_vector_type(8)));
typedef unsigned int   ui4 __attribute__((ext_vector_type(4)));

#define TAGM 0x80008000u
#define CLRM 0x7FFF7FFFu

__device__ __forceinline__ unsigned short f2bf(float f) {
    uint32_t u = __float_as_uint(f);
    uint32_t r = (u + 0x7fffu + ((u >> 16) & 1u)) >> 16;   // RNE
    return (unsigned short)r;
}

// Agent-coherent 16B load (bypass L1+L2, read at LLC). Issue-only; completion
// claimed by explicit counted s_waitcnt.
__device__ __forceinline__ ui4 ld_u128_agent(const void* p) {
    ui4 v;
    asm volatile("global_load_dwordx4 %0, %1, off sc0 sc1"
                 : "=v"(v) : "v"(p) : "memory");
    return v;
}

// Swizzled LDS fragment load: 16B at row*stride + (kbyte ^ ((row&7)<<4))
__device__ __forceinline__ bf16x8 ld_frag(const unsigned short* smem, int row, int kbyte, int rowstride) {
    int off = row * rowstride + (kbyte ^ ((row & 7) << 4));
    return *reinterpret_cast<const bf16x8*>(reinterpret_cast<const char*>(smem) + off);
}
__device__ __forceinline__ us8 ld_frag_u(const unsigned short* smem, int row, int kbyte, int rowstride) {
    int off = row * rowstride + (kbyte ^ ((row & 7) << 4));
    return *reinterpret_cast<const us8*>(reinterpret_cast<const char*>(smem) + off);
}

__global__ __launch_bounds__(256, 1) void rnn_persistent(
    const float* __restrict__ seqs, const float* __restrict__ W_ih,
    const float* __restrict__ W_hh, const float* __restrict__ b_ih,
    const float* __restrict__ b_hh, const float* __restrict__ W_fc,
    const float* __restrict__ b_fc, float* __restrict__ out,
    unsigned short* __restrict__ hbuf)   // [2][128][1024] bf16, zeroed each call
{
    const int tid  = threadIdx.x;
    const int lane = tid & 63;
    const int wv   = tid >> 6;          // wave 0..3 (K-split)
    const int wg   = blockIdx.x;
    const int g    = wg >> 5;           // batch group 0..7 (rows g*16..+15)
    const int w    = wg & 31;           // col slice (cols w*32..+31)
    const int gr0  = g * 16;
    const int c0   = w * 32;
    const int ln15 = lane & 15;
    const int lk   = lane >> 4;

    __shared__ unsigned short xtile[16 * 512];   // 16KB, swizzled bf16
    __shared__ unsigned short htile[16 * 1024];  // 32KB, swizzled bf16
    __shared__ float red[4][16][33];             // wave partials (+1 pad)
    __shared__ float biasS[32];

    // ---- init: weight B-fragments into registers (bf16) ----
    bf16x8 wih[2][4];
    bf16x8 whh[2][8];
    #pragma unroll
    for (int nt = 0; nt < 2; nt++) {
        const int j = c0 + nt * 16 + ln15;
        #pragma unroll
        for (int s = 0; s < 4; s++) {
            const int k = wv * 128 + s * 32 + lk * 8;
            const float* p = W_ih + j * IN + k;
            us8 u;
            #pragma unroll
            for (int e = 0; e < 8; e++) u[e] = f2bf(p[e]);
            wih[nt][s] = __builtin_bit_cast(bf16x8, u);
        }
        #pragma unroll
        for (int s = 0; s < 8; s++) {
            const int k = wv * 256 + s * 32 + lk * 8;
            const float* p = W_hh + j * HID + k;
            us8 u;
            #pragma unroll
            for (int e = 0; e < 8; e++) u[e] = f2bf(p[e]);
            whh[nt][s] = __builtin_bit_cast(bf16x8, u);
        }
    }
    if (tid < 32) biasS[tid] = b_ih[c0 + tid] + b_hh[c0 + tid];

    // per-thread h chunk offsets (16B chunks, 128 per row of [16][1024])
    int hgoff[8], hloff[8];
    #pragma unroll
    for (int it = 0; it < 8; it++) {
        const int c    = tid + it * 256;
        const int row  = c >> 7;
        const int colc = c & 127;
        hgoff[it] = row * 2048 + colc * 16;
        hloff[it] = row * 2048 + ((colc * 16) ^ ((row & 7) << 4));
    }

    // per-thread x chunk coords (16B chunks, 64 per row)
    const int xrow[4] = { (tid) >> 6, (tid + 256) >> 6, (tid + 512) >> 6, (tid + 768) >> 6 };
    const int xcol[4] = { (tid) & 63, (tid + 256) & 63, (tid + 512) & 63, (tid + 768) & 63 };

    // ---- prologue: load + convert x(0) ----
    us8 xbf[4];
    {
        const float* xsrc = seqs + (size_t)gr0 * IN;
        #pragma unroll
        for (int it = 0; it < 4; it++) {
            const float* s4 = xsrc + xrow[it] * IN + xcol[it] * 8;
            float4 a = *reinterpret_cast<const float4*>(s4);
            float4 b = *reinterpret_cast<const float4*>(s4 + 4);
            us8 u;
            u[0]=f2bf(a.x); u[1]=f2bf(a.y); u[2]=f2bf(a.z); u[3]=f2bf(a.w);
            u[4]=f2bf(b.x); u[5]=f2bf(b.y); u[6]=f2bf(b.z); u[7]=f2bf(b.w);
            xbf[it] = u;
        }
    }

    const size_t slotB = (size_t)BATCH * HID * 2;   // 256KB per ring slot
    char* hbase = reinterpret_cast<char*>(hbuf);

    for (int t = 0; t < T_STEPS; t++) {
        // 1: write prepared x(t) -> xtile (swizzled)
        #pragma unroll
        for (int it = 0; it < 4; it++) {
            const int off = xrow[it] * 1024 + ((xcol[it] * 16) ^ ((xrow[it] & 7) << 4));
            *reinterpret_cast<us8*>(reinterpret_cast<char*>(xtile) + off) = xbf[it];
        }
        __syncthreads();

        // 3: issue 8 agent h-poll loads FIRST (oldest -> claimable by vmcnt(8))
        ui4 hv[8];
        const char* hsrc = hbase + (size_t)(t & 1) * slotB + (size_t)gr0 * HID * 2;
        if (t > 0) {
            #pragma unroll
            for (int it = 0; it < 8; it++) hv[it] = ld_u128_agent(hsrc + hgoff[it]);
        }
        __builtin_amdgcn_sched_barrier(0);

        // 4: issue 8 plain x(t+1) loads (stay in flight across vmcnt(8))
        float4 xr[8];
        {
            const int tn = (t + 1 < T_STEPS) ? t + 1 : t;
            const float* xsrc = seqs + (size_t)tn * (BATCH * IN) + (size_t)gr0 * IN;
            #pragma unroll
            for (int it = 0; it < 4; it++) {
                const float* s4 = xsrc + xrow[it] * IN + xcol[it] * 8;
                xr[2*it]   = *reinterpret_cast<const float4*>(s4);
                xr[2*it+1] = *reinterpret_cast<const float4*>(s4 + 4);
            }
        }
        __builtin_amdgcn_sched_barrier(0);

        // 5: x-projection MFMAs (overlap first h poll round trip)
        f32x4 acc0 = {0.f, 0.f, 0.f, 0.f};
        f32x4 acc1 = {0.f, 0.f, 0.f, 0.f};
        {
            const int kx0b = wv * 256;
            #pragma unroll
            for (int s = 0; s < 4; s++) {
                bf16x8 a = ld_frag(xtile, ln15, kx0b + s * 64 + lk * 16, 1024);
                acc0 = __builtin_amdgcn_mfma_f32_16x16x32_bf16(a, wih[0][s], acc0, 0, 0, 0);
                acc1 = __builtin_amdgcn_mfma_f32_16x16x32_bf16(a, wih[1][s], acc1, 0, 0, 0);
            }
        }

        if (t > 0) {
            // 6: claim h loads (prev h-store + 8 h = 9 oldest; 8 x remain in flight)
            const unsigned pr = ((t >> 1) & 1) ? 0x80000000u : 0x00008000u;
            asm volatile("s_waitcnt vmcnt(8)" ::: "memory");
            __builtin_amdgcn_sched_barrier(0);
            unsigned pending = 0xFFu;
            while (true) {
                unsigned np = 0;
                #pragma unroll
                for (int it = 0; it < 8; it++) {
                    if (pending & (1u << it)) {
                        unsigned d = ((hv[it][0] & TAGM) ^ pr) | ((hv[it][1] & TAGM) ^ pr)
                                   | ((hv[it][2] & TAGM) ^ pr) | ((hv[it][3] & TAGM) ^ pr);
                        if (d != 0u) {
                            np |= (1u << it);
                            hv[it] = ld_u128_agent(hsrc + hgoff[it]);
                        }
                    }
                }
                pending = np;
                if (pending == 0u) break;
                asm volatile("s_waitcnt vmcnt(0)" ::: "memory");   // rare: only while blocked
                __builtin_amdgcn_sched_barrier(0);
            }
            // strip epoch tags, stage htile (swizzled)
            #pragma unroll
            for (int it = 0; it < 8; it++) {
                ui4 v = hv[it];
                v[0] &= CLRM; v[1] &= CLRM; v[2] &= CLRM; v[3] &= CLRM;
                *reinterpret_cast<ui4*>(reinterpret_cast<char*>(htile) + hloff[it]) = v;
            }
            __syncthreads();

            // 8: recurrence MFMAs
            const int kh0b = wv * 512;
            #pragma unroll
            for (int s = 0; s < 8; s++) {
                bf16x8 a = ld_frag(htile, ln15, kh0b + s * 64 + lk * 16, 2048);
                acc0 = __builtin_amdgcn_mfma_f32_16x16x32_bf16(a, whh[0][s], acc0, 0, 0, 0);
                acc1 = __builtin_amdgcn_mfma_f32_16x16x32_bf16(a, whh[1][s], acc1, 0, 0, 0);
            }
        }

        // 9: cross-wave K-reduction -> relu
        #pragma unroll
        for (int r = 0; r < 4; r++) {
            red[wv][lk * 4 + r][ln15]      = acc0[r];
            red[wv][lk * 4 + r][16 + ln15] = acc1[r];
        }
        __syncthreads();
        const int hrow = tid >> 4;          // 0..15
        const int co2  = (tid & 15) * 2;    // even col within slice
        float v0 = red[0][hrow][co2]   + red[1][hrow][co2]   + red[2][hrow][co2]   + red[3][hrow][co2]   + biasS[co2];
        float v1 = red[0][hrow][co2+1] + red[1][hrow][co2+1] + red[2][hrow][co2+1] + red[3][hrow][co2+1] + biasS[co2+1];
        v0 = fmaxf(v0, 0.0f);
        v1 = fmaxf(v1, 0.0f);

        // 10: claim x(t+1) (only the 8 x-loads are outstanding), convert
        asm volatile("s_waitcnt vmcnt(0)" ::: "memory");
        __builtin_amdgcn_sched_barrier(0);
        #pragma unroll
        for (int it = 0; it < 4; it++) {
            float4 a = xr[2*it], b = xr[2*it+1];
            us8 u;
            u[0]=f2bf(a.x); u[1]=f2bf(a.y); u[2]=f2bf(a.z); u[3]=f2bf(a.w);
            u[4]=f2bf(b.x); u[5]=f2bf(b.y); u[6]=f2bf(b.z); u[7]=f2bf(b.w);
            xbf[it] = u;
        }

        // 12: store epoch-tagged H_{t+1} (no drain, no flag!)
        {
            const unsigned pw = (((t + 1) >> 1) & 1) ? 0x80000000u : 0x00008000u;
            unsigned pack = (unsigned)f2bf(v0) | ((unsigned)f2bf(v1) << 16) | pw;
            unsigned* dst = reinterpret_cast<unsigned*>(
                hbase + (size_t)((t + 1) & 1) * slotB
                + ((size_t)(gr0 + hrow) * HID + c0 + co2) * 2);
            __hip_atomic_store(dst, pack, __ATOMIC_RELAXED, __HIP_MEMORY_SCOPE_AGENT);
        }
    }

    // ---- FC epilogue: poll H_512 (slot 0, epoch 1 -> tag 0x00008000) ----
    {
        const char* hsrc = hbase + (size_t)gr0 * HID * 2;
        ui4 hv[8];
        #pragma unroll
        for (int it = 0; it < 8; it++) hv[it] = ld_u128_agent(hsrc + hgoff[it]);
        unsigned pending = 0xFFu;
        do {
            asm volatile("s_waitcnt vmcnt(0)" ::: "memory");
            __builtin_amdgcn_sched_barrier(0);
            unsigned np = 0;
            #pragma unroll
            for (int it = 0; it < 8; it++) {
                if (pending & (1u << it)) {
                    unsigned d = ((hv[it][0] & TAGM) ^ 0x00008000u) | ((hv[it][1] & TAGM) ^ 0x00008000u)
                               | ((hv[it][2] & TAGM) ^ 0x00008000u) | ((hv[it][3] & TAGM) ^ 0x00008000u);
                    if (d != 0u) {
                        np |= (1u << it);
                        hv[it] = ld_u128_agent(hsrc + hgoff[it]);
                    }
                }
            }
            pending = np;
        } while (pending);
        #pragma unroll
        for (int it = 0; it < 8; it++) {
            ui4 v = hv[it];
            v[0] &= CLRM; v[1] &= CLRM; v[2] &= CLRM; v[3] &= CLRM;
            *reinterpret_cast<ui4*>(reinterpret_cast<char*>(htile) + hloff[it]) = v;
        }
        __syncthreads();
    }

    // out[gr0+row][w*8+oc] = sum_k htile[row][k]*W_fc[o][k] + b_fc[o]; 2-way K-split
    {
        const int oi   = tid & 127;
        const int half = tid >> 7;
        const int row  = oi >> 3;
        const int o    = w * 8 + (oi & 7);
        const float* wf = W_fc + (size_t)o * HID + half * 512;
        float sum = 0.f;
        #pragma unroll 4
        for (int ck = 0; ck < 64; ck++) {
            us8 hu = ld_frag_u(htile, row, half * 1024 + ck * 16, 2048);
            float4 wa = *reinterpret_cast<const float4*>(wf + ck * 8);
            float4 wb = *reinterpret_cast<const float4*>(wf + ck * 8 + 4);
            sum += __uint_as_float((unsigned)hu[0] << 16) * wa.x
                 + __uint_as_float((unsigned)hu[1] << 16) * wa.y
                 + __uint_as_float((unsigned)hu[2] << 16) * wa.z
                 + __uint_as_float((unsigned)hu[3] << 16) * wa.w
                 + __uint_as_float((unsigned)hu[4] << 16) * wb.x
                 + __uint_as_float((unsigned)hu[5] << 16) * wb.y
                 + __uint_as_float((unsigned)hu[6] << 16) * wb.z
                 + __uint_as_float((unsigned)hu[7] << 16) * wb.w;
        }
        float* redf = &red[0][0][0];
        redf[tid] = sum;
        __syncthreads();
        if (tid < 128) {
            out[(size_t)(gr0 + row) * OUTN + o] = redf[tid] + redf[tid + 128] + b_fc[o];
        }
    }
}

extern "C" void kernel_launch(void* const* d_in, const int* in_sizes, int n_in,
                              void* d_out, int out_size, void* d_ws, size_t ws_size,
                              hipStream_t stream) {
    const float* seqs = (const float*)d_in[0];
    const float* W_ih = (const float*)d_in[1];
    const float* W_hh = (const float*)d_in[2];
    const float* b_ih = (const float*)d_in[3];
    const float* b_hh = (const float*)d_in[4];
    const float* W_fc = (const float*)d_in[5];
    const float* b_fc = (const float*)d_in[6];
    float* out = (float*)d_out;

    unsigned short* hbuf = (unsigned short*)d_ws;   // 2*128*1024*2 = 524288 B ring

    // Zero the ring every call: epoch bits {1,2} never match zeros, so no
    // stale-data hazard across graph replays or on the first (unpoisoned) call.
    hipMemsetAsync(hbuf, 0, 2 * BATCH * HID * sizeof(unsigned short), stream);
    rnn_persistent<<<dim3(256), dim3(256), 0, stream>>>(
        seqs, W_ih, W_hh, b_ih, b_hh, W_fc, b_fc, out, hbuf);
}